// Round 1
// baseline (6910.781 us; speedup 1.0000x reference)
//
#include <hip/hip_runtime.h>

// GNODecoder: per-edge MLP (6->64->64->128, gelu) * gathered source features,
// scatter-mean over queries, then per-query projection MLP (128->256->4).
// All fp32. Strategy: lane-per-edge / lane-per-query, register-blocked FMAs,
// wave-uniform weight access (scalarizes to s_load), fp32 atomics for scatter.

__device__ __forceinline__ float gelu_f(float x) {
    // jax.nn.gelu default (approximate=True, tanh form)
    float x3 = x * x * x;
    float t  = 0.7978845608028654f * fmaf(0.044715f, x3, x);
    // tanh(t) = 1 - 2/(exp(2t)+1)
    float e  = __expf(2.0f * t);
    float r  = __builtin_amdgcn_rcpf(e + 1.0f);
    return 0.5f * x * (1.0f + (1.0f - 2.0f * r));
}

__global__ __launch_bounds__(256, 2) void edge_kernel(
    const float* __restrict__ rndata,   // [NL,128]
    const float* __restrict__ qpos,     // [NQ,3]
    const float* __restrict__ lpos,     // [NL,3]
    const int*   __restrict__ dst,      // [E]
    const int*   __restrict__ src,      // [E]
    const float* __restrict__ W0, const float* __restrict__ b0,   // [6,64],[64]
    const float* __restrict__ W1, const float* __restrict__ b1,   // [64,64],[64]
    const float* __restrict__ W2, const float* __restrict__ b2,   // [64,128],[128]
    float* __restrict__ agg,            // [NQ,128] accumulators (pre-zeroed)
    float* __restrict__ cnt,            // [NQ] counts (pre-zeroed)
    int E)
{
    int e = blockIdx.x * blockDim.x + threadIdx.x;
    if (e >= E) return;
    int d = dst[e];
    int s = src[e];

    float q0 = qpos[d * 3 + 0], q1 = qpos[d * 3 + 1], q2 = qpos[d * 3 + 2];
    float l0 = lpos[s * 3 + 0], l1 = lpos[s * 3 + 1], l2 = lpos[s * 3 + 2];

    // ---- layer 0: [6] -> [64], gelu ----
    float h0[64];
#pragma unroll
    for (int j = 0; j < 64; ++j) {
        float a = b0[j];
        a = fmaf(q0, W0[0 * 64 + j], a);
        a = fmaf(q1, W0[1 * 64 + j], a);
        a = fmaf(q2, W0[2 * 64 + j], a);
        a = fmaf(l0, W0[3 * 64 + j], a);
        a = fmaf(l1, W0[4 * 64 + j], a);
        a = fmaf(l2, W0[5 * 64 + j], a);
        h0[j] = gelu_f(a);
    }

    // ---- layer 1: [64] -> [64], gelu ----
    // outer loop fully unrolled so h1[] stays in registers (constant indices)
    float h1[64];
#pragma unroll
    for (int jj = 0; jj < 64; jj += 8) {
        float acc[8];
#pragma unroll
        for (int u = 0; u < 8; ++u) acc[u] = b1[jj + u];
#pragma unroll
        for (int i = 0; i < 64; ++i) {
            float h = h0[i];
#pragma unroll
            for (int u = 0; u < 8; ++u)
                acc[u] = fmaf(h, W1[i * 64 + jj + u], acc[u]);
        }
#pragma unroll
        for (int u = 0; u < 8; ++u) h1[jj + u] = gelu_f(acc[u]);
    }

    // ---- layer 2: [64] -> [128], * rndata[src], scatter-add ----
    const float* rsrc = rndata + (size_t)s * 128;
    float*       aggd = agg    + (size_t)d * 128;
#pragma unroll 1
    for (int jj = 0; jj < 128; jj += 8) {
        float acc[8];
#pragma unroll
        for (int u = 0; u < 8; ++u) acc[u] = b2[jj + u];
#pragma unroll
        for (int i = 0; i < 64; ++i) {
            float h = h1[i];
#pragma unroll
            for (int u = 0; u < 8; ++u)
                acc[u] = fmaf(h, W2[i * 128 + jj + u], acc[u]);
        }
#pragma unroll
        for (int u = 0; u < 8; ++u) {
            atomicAdd(&aggd[jj + u], acc[u] * rsrc[jj + u]);
        }
    }
    atomicAdd(&cnt[d], 1.0f);
}

__global__ __launch_bounds__(256, 2) void proj_kernel(
    const float* __restrict__ agg,      // [NQ,128] sums
    const float* __restrict__ cnt,      // [NQ]
    const float* __restrict__ P0, const float* __restrict__ pb0,  // [128,256],[256]
    const float* __restrict__ P1, const float* __restrict__ pb1,  // [256,4],[4]
    float* __restrict__ out,            // [NQ,4]
    int nq)
{
    int q = blockIdx.x * blockDim.x + threadIdx.x;
    if (q >= nq) return;

    float c   = cnt[q];
    float inv = 1.0f / fmaxf(c, 1.0f);

    float a[128];
    const float4* ag4 = (const float4*)(agg + (size_t)q * 128);
#pragma unroll
    for (int i = 0; i < 32; ++i) {
        float4 v = ag4[i];
        a[4 * i + 0] = v.x * inv;
        a[4 * i + 1] = v.y * inv;
        a[4 * i + 2] = v.z * inv;
        a[4 * i + 3] = v.w * inv;
    }

    float o0 = pb1[0], o1 = pb1[1], o2 = pb1[2], o3 = pb1[3];
#pragma unroll 1
    for (int jj = 0; jj < 256; jj += 8) {
        float acc[8];
#pragma unroll
        for (int u = 0; u < 8; ++u) acc[u] = pb0[jj + u];
#pragma unroll
        for (int i = 0; i < 128; ++i) {
            float av = a[i];
#pragma unroll
            for (int u = 0; u < 8; ++u)
                acc[u] = fmaf(av, P0[i * 256 + jj + u], acc[u]);
        }
#pragma unroll
        for (int u = 0; u < 8; ++u) {
            float h = gelu_f(acc[u]);
            o0 = fmaf(h, P1[(jj + u) * 4 + 0], o0);
            o1 = fmaf(h, P1[(jj + u) * 4 + 1], o1);
            o2 = fmaf(h, P1[(jj + u) * 4 + 2], o2);
            o3 = fmaf(h, P1[(jj + u) * 4 + 3], o3);
        }
    }
    float4* o4 = (float4*)(out + (size_t)q * 4);
    *o4 = make_float4(o0, o1, o2, o3);
}

extern "C" void kernel_launch(void* const* d_in, const int* in_sizes, int n_in,
                              void* d_out, int out_size, void* d_ws, size_t ws_size,
                              hipStream_t stream)
{
    const float* rndata = (const float*)d_in[0];
    const float* qpos   = (const float*)d_in[1];
    const float* lpos   = (const float*)d_in[2];
    const int*   dst    = (const int*)d_in[3];
    const int*   src    = (const int*)d_in[4];
    const float* W0  = (const float*)d_in[5];
    const float* b0  = (const float*)d_in[6];
    const float* W1  = (const float*)d_in[7];
    const float* b1  = (const float*)d_in[8];
    const float* W2  = (const float*)d_in[9];
    const float* b2  = (const float*)d_in[10];
    const float* P0  = (const float*)d_in[11];
    const float* pb0 = (const float*)d_in[12];
    const float* P1  = (const float*)d_in[13];
    const float* pb1 = (const float*)d_in[14];

    int nq = in_sizes[1] / 3;
    int E  = in_sizes[3];

    float* agg = (float*)d_ws;                 // [nq,128]
    float* cnt = agg + (size_t)nq * 128;       // [nq]

    // zero accumulators (ws is poisoned to 0xAA before every call)
    hipMemsetAsync(d_ws, 0, (size_t)nq * 129 * sizeof(float), stream);

    edge_kernel<<<(E + 255) / 256, 256, 0, stream>>>(
        rndata, qpos, lpos, dst, src,
        W0, b0, W1, b1, W2, b2, agg, cnt, E);

    proj_kernel<<<(nq + 255) / 256, 256, 0, stream>>>(
        agg, cnt, P0, pb0, P1, pb1, (float*)d_out, nq);
}

// Round 2
// 6878.180 us; speedup vs baseline: 1.0047x; 1.0047x over previous
//
#include <hip/hip_runtime.h>

// GNODecoder, round 2: counting-sort edges by dst to kill the scattered-atomic
// wall (4 GB of 32B-granule atomic RMW traffic @650 GB/s was 6.7 ms of the
// 6.9 ms total). Sorted edges -> rep[E,128] written with plain coalesced
// stores, then contiguous segmented mean per query. Fallback to atomic path
// if ws_size is too small.

__device__ __forceinline__ float gelu_f(float x) {
    // jax.nn.gelu default (approximate=True, tanh form)
    float x3 = x * x * x;
    float t  = 0.7978845608028654f * fmaf(0.044715f, x3, x);
    float e  = __expf(2.0f * t);
    float r  = __builtin_amdgcn_rcpf(e + 1.0f);
    return 0.5f * x * (1.0f + (1.0f - 2.0f * r));
}

// ---------- sort machinery ----------

__global__ void hist_kernel(const int* __restrict__ dst, int* __restrict__ hist, int E) {
    int e = blockIdx.x * blockDim.x + threadIdx.x;
    if (e < E) atomicAdd(&hist[dst[e]], 1);
}

// exclusive scan of hist[0..n-1] -> start[0..n], single 1024-thread workgroup
__global__ __launch_bounds__(1024) void scan_kernel(const int* __restrict__ hist,
                                                    int* __restrict__ start, int n) {
    __shared__ int wsum[16];
    __shared__ int woff[17];
    int tid = threadIdx.x;
    int lane = tid & 63, wid = tid >> 6;
    int carry = 0;  // meaningful on tid 0 only
    for (int base = 0; base < n; base += 1024) {
        int i = base + tid;
        int v = (i < n) ? hist[i] : 0;
        int incl = v;
#pragma unroll
        for (int off = 1; off < 64; off <<= 1) {
            int t = __shfl_up(incl, off, 64);
            if (lane >= off) incl += t;
        }
        if (lane == 63) wsum[wid] = incl;
        __syncthreads();
        if (tid == 0) {
            int acc = carry;
#pragma unroll
            for (int w = 0; w < 16; ++w) { woff[w] = acc; acc += wsum[w]; }
            carry = acc;
        }
        __syncthreads();
        if (i < n) start[i] = woff[wid] + incl - v;  // exclusive
        __syncthreads();  // woff/wsum reusable next iteration
    }
    if (threadIdx.x == 0) start[n] = carry;
}

__global__ void scatter_kernel(const int* __restrict__ dst, const int* __restrict__ src,
                               const int* __restrict__ start, int* __restrict__ cursor,
                               int* __restrict__ dsts, int* __restrict__ srcs, int E) {
    int e = blockIdx.x * blockDim.x + threadIdx.x;
    if (e >= E) return;
    int d = dst[e];
    int pos = start[d] + atomicAdd(&cursor[d], 1);
    dsts[pos] = d;
    srcs[pos] = src[e];
}

// ---------- sorted path: per-edge MLP -> rep (no atomics) ----------

__global__ __launch_bounds__(256) void edge_sorted_kernel(
    const float* __restrict__ rndata,   // [NL,128]
    const float* __restrict__ qpos,     // [NQ,3]
    const float* __restrict__ lpos,     // [NL,3]
    const int*   __restrict__ dsts,     // [E] sorted by dst
    const int*   __restrict__ srcs,     // [E] matching
    const float* __restrict__ W0, const float* __restrict__ b0,
    const float* __restrict__ W1, const float* __restrict__ b1,
    const float* __restrict__ W2, const float* __restrict__ b2,
    float* __restrict__ rep,            // [E,128]
    int E)
{
    int i = blockIdx.x * blockDim.x + threadIdx.x;
    if (i >= E) return;
    int d = dsts[i];
    int s = srcs[i];

    float q0 = qpos[d * 3 + 0], q1 = qpos[d * 3 + 1], q2 = qpos[d * 3 + 2];
    float l0 = lpos[s * 3 + 0], l1 = lpos[s * 3 + 1], l2 = lpos[s * 3 + 2];

    // layer 0: [6] -> [64], gelu
    float h0[64];
#pragma unroll
    for (int j = 0; j < 64; ++j) {
        float a = b0[j];
        a = fmaf(q0, W0[0 * 64 + j], a);
        a = fmaf(q1, W0[1 * 64 + j], a);
        a = fmaf(q2, W0[2 * 64 + j], a);
        a = fmaf(l0, W0[3 * 64 + j], a);
        a = fmaf(l1, W0[4 * 64 + j], a);
        a = fmaf(l2, W0[5 * 64 + j], a);
        h0[j] = gelu_f(a);
    }

    // layer 1: [64] -> [64], gelu
    float h1[64];
#pragma unroll
    for (int jj = 0; jj < 64; jj += 8) {
        float acc[8];
#pragma unroll
        for (int u = 0; u < 8; ++u) acc[u] = b1[jj + u];
#pragma unroll
        for (int i2 = 0; i2 < 64; ++i2) {
            float h = h0[i2];
#pragma unroll
            for (int u = 0; u < 8; ++u)
                acc[u] = fmaf(h, W1[i2 * 64 + jj + u], acc[u]);
        }
#pragma unroll
        for (int u = 0; u < 8; ++u) h1[jj + u] = gelu_f(acc[u]);
    }

    // layer 2: [64] -> [128], * rndata[src], plain store
    const float4* r4 = (const float4*)(rndata + (size_t)s * 128);
    float4*       o4 = (float4*)(rep + (size_t)i * 128);
#pragma unroll 1
    for (int jj = 0; jj < 128; jj += 8) {
        float acc[8];
#pragma unroll
        for (int u = 0; u < 8; ++u) acc[u] = b2[jj + u];
#pragma unroll
        for (int i2 = 0; i2 < 64; ++i2) {
            float h = h1[i2];
#pragma unroll
            for (int u = 0; u < 8; ++u)
                acc[u] = fmaf(h, W2[i2 * 128 + jj + u], acc[u]);
        }
        float4 ra = r4[jj / 4], rb = r4[jj / 4 + 1];
        o4[jj / 4]     = make_float4(acc[0] * ra.x, acc[1] * ra.y, acc[2] * ra.z, acc[3] * ra.w);
        o4[jj / 4 + 1] = make_float4(acc[4] * rb.x, acc[5] * rb.y, acc[6] * rb.z, acc[7] * rb.w);
    }
}

// segmented mean: thread t handles (q = t>>5, 4 channels c4 = t&31)
__global__ __launch_bounds__(256) void agg_kernel(
    const float* __restrict__ rep, const int* __restrict__ start,
    float* __restrict__ agg, int nq)
{
    int t = blockIdx.x * blockDim.x + threadIdx.x;
    if (t >= nq * 32) return;
    int q = t >> 5, c4 = t & 31;
    int s0 = start[q], s1 = start[q + 1];
    float ax = 0.f, ay = 0.f, az = 0.f, aw = 0.f;
    const float4* r4 = (const float4*)rep;
    for (int r = s0; r < s1; ++r) {
        float4 v = r4[(size_t)r * 32 + c4];
        ax += v.x; ay += v.y; az += v.z; aw += v.w;
    }
    float inv = 1.0f / fmaxf((float)(s1 - s0), 1.0f);
    ((float4*)agg)[(size_t)q * 32 + c4] = make_float4(ax * inv, ay * inv, az * inv, aw * inv);
}

// ---------- fallback atomic path (ws too small) ----------

__global__ __launch_bounds__(256) void edge_atomic_kernel(
    const float* __restrict__ rndata, const float* __restrict__ qpos,
    const float* __restrict__ lpos, const int* __restrict__ dst,
    const int* __restrict__ src,
    const float* __restrict__ W0, const float* __restrict__ b0,
    const float* __restrict__ W1, const float* __restrict__ b1,
    const float* __restrict__ W2, const float* __restrict__ b2,
    float* __restrict__ agg, float* __restrict__ cnt, int E)
{
    int e = blockIdx.x * blockDim.x + threadIdx.x;
    if (e >= E) return;
    int d = dst[e];
    int s = src[e];
    float q0 = qpos[d * 3 + 0], q1 = qpos[d * 3 + 1], q2 = qpos[d * 3 + 2];
    float l0 = lpos[s * 3 + 0], l1 = lpos[s * 3 + 1], l2 = lpos[s * 3 + 2];
    float h0[64];
#pragma unroll
    for (int j = 0; j < 64; ++j) {
        float a = b0[j];
        a = fmaf(q0, W0[0 * 64 + j], a);
        a = fmaf(q1, W0[1 * 64 + j], a);
        a = fmaf(q2, W0[2 * 64 + j], a);
        a = fmaf(l0, W0[3 * 64 + j], a);
        a = fmaf(l1, W0[4 * 64 + j], a);
        a = fmaf(l2, W0[5 * 64 + j], a);
        h0[j] = gelu_f(a);
    }
    float h1[64];
#pragma unroll
    for (int jj = 0; jj < 64; jj += 8) {
        float acc[8];
#pragma unroll
        for (int u = 0; u < 8; ++u) acc[u] = b1[jj + u];
#pragma unroll
        for (int i2 = 0; i2 < 64; ++i2) {
            float h = h0[i2];
#pragma unroll
            for (int u = 0; u < 8; ++u) acc[u] = fmaf(h, W1[i2 * 64 + jj + u], acc[u]);
        }
#pragma unroll
        for (int u = 0; u < 8; ++u) h1[jj + u] = gelu_f(acc[u]);
    }
    const float* rsrc = rndata + (size_t)s * 128;
    float*       aggd = agg + (size_t)d * 128;
#pragma unroll 1
    for (int jj = 0; jj < 128; jj += 8) {
        float acc[8];
#pragma unroll
        for (int u = 0; u < 8; ++u) acc[u] = b2[jj + u];
#pragma unroll
        for (int i2 = 0; i2 < 64; ++i2) {
            float h = h1[i2];
#pragma unroll
            for (int u = 0; u < 8; ++u) acc[u] = fmaf(h, W2[i2 * 128 + jj + u], acc[u]);
        }
#pragma unroll
        for (int u = 0; u < 8; ++u) atomicAdd(&aggd[jj + u], acc[u] * rsrc[jj + u]);
    }
    atomicAdd(&cnt[d], 1.0f);
}

// ---------- projection ----------

__global__ __launch_bounds__(256) void proj_kernel(
    const float* __restrict__ agg,      // [NQ,128] (already mean if cnt==null)
    const float* __restrict__ cnt,      // [NQ] or nullptr
    const float* __restrict__ P0, const float* __restrict__ pb0,
    const float* __restrict__ P1, const float* __restrict__ pb1,
    float* __restrict__ out, int nq)
{
    int q = blockIdx.x * blockDim.x + threadIdx.x;
    if (q >= nq) return;

    float inv = 1.0f;
    if (cnt) inv = 1.0f / fmaxf(cnt[q], 1.0f);

    float a[128];
    const float4* ag4 = (const float4*)(agg + (size_t)q * 128);
#pragma unroll
    for (int i = 0; i < 32; ++i) {
        float4 v = ag4[i];
        a[4 * i + 0] = v.x * inv;
        a[4 * i + 1] = v.y * inv;
        a[4 * i + 2] = v.z * inv;
        a[4 * i + 3] = v.w * inv;
    }

    float o0 = pb1[0], o1 = pb1[1], o2 = pb1[2], o3 = pb1[3];
#pragma unroll 1
    for (int jj = 0; jj < 256; jj += 8) {
        float acc[8];
#pragma unroll
        for (int u = 0; u < 8; ++u) acc[u] = pb0[jj + u];
#pragma unroll
        for (int i = 0; i < 128; ++i) {
            float av = a[i];
#pragma unroll
            for (int u = 0; u < 8; ++u)
                acc[u] = fmaf(av, P0[i * 256 + jj + u], acc[u]);
        }
#pragma unroll
        for (int u = 0; u < 8; ++u) {
            float h = gelu_f(acc[u]);
            o0 = fmaf(h, P1[(jj + u) * 4 + 0], o0);
            o1 = fmaf(h, P1[(jj + u) * 4 + 1], o1);
            o2 = fmaf(h, P1[(jj + u) * 4 + 2], o2);
            o3 = fmaf(h, P1[(jj + u) * 4 + 3], o3);
        }
    }
    float4* o4 = (float4*)(out + (size_t)q * 4);
    *o4 = make_float4(o0, o1, o2, o3);
}

extern "C" void kernel_launch(void* const* d_in, const int* in_sizes, int n_in,
                              void* d_out, int out_size, void* d_ws, size_t ws_size,
                              hipStream_t stream)
{
    const float* rndata = (const float*)d_in[0];
    const float* qpos   = (const float*)d_in[1];
    const float* lpos   = (const float*)d_in[2];
    const int*   dst    = (const int*)d_in[3];
    const int*   src    = (const int*)d_in[4];
    const float* W0  = (const float*)d_in[5];
    const float* b0  = (const float*)d_in[6];
    const float* W1  = (const float*)d_in[7];
    const float* b1  = (const float*)d_in[8];
    const float* W2  = (const float*)d_in[9];
    const float* b2  = (const float*)d_in[10];
    const float* P0  = (const float*)d_in[11];
    const float* pb0 = (const float*)d_in[12];
    const float* P1  = (const float*)d_in[13];
    const float* pb1 = (const float*)d_in[14];

    int nq = in_sizes[1] / 3;
    int E  = in_sizes[3];

    // sorted-path workspace layout (16B-aligned chunks)
    size_t off = 0;
    auto alloc = [&](size_t bytes) {
        void* p = (char*)d_ws + off;
        off += (bytes + 15) & ~(size_t)15;
        return p;
    };
    float* rep    = (float*)alloc((size_t)E * 128 * sizeof(float));
    float* agg    = (float*)alloc((size_t)nq * 128 * sizeof(float));
    int*   hist   = (int*)alloc((size_t)nq * sizeof(int));
    int*   cursor = (int*)alloc((size_t)nq * sizeof(int));
    int*   start  = (int*)alloc((size_t)(nq + 1) * sizeof(int));
    int*   dsts   = (int*)alloc((size_t)E * sizeof(int));
    int*   srcs   = (int*)alloc((size_t)E * sizeof(int));
    bool sorted_fits = off <= ws_size;

    if (sorted_fits) {
        // zero hist + cursor (adjacent allocations)
        hipMemsetAsync(hist, 0, 2 * (((size_t)nq * sizeof(int) + 15) & ~(size_t)15), stream);
        hist_kernel<<<(E + 255) / 256, 256, 0, stream>>>(dst, hist, E);
        scan_kernel<<<1, 1024, 0, stream>>>(hist, start, nq);
        scatter_kernel<<<(E + 255) / 256, 256, 0, stream>>>(dst, src, start, cursor, dsts, srcs, E);
        edge_sorted_kernel<<<(E + 255) / 256, 256, 0, stream>>>(
            rndata, qpos, lpos, dsts, srcs, W0, b0, W1, b1, W2, b2, rep, E);
        agg_kernel<<<((size_t)nq * 32 + 255) / 256, 256, 0, stream>>>(rep, start, agg, nq);
        proj_kernel<<<(nq + 255) / 256, 256, 0, stream>>>(
            agg, nullptr, P0, pb0, P1, pb1, (float*)d_out, nq);
    } else {
        // fallback: atomic path (round-1 kernel)
        float* fagg = (float*)d_ws;
        float* fcnt = fagg + (size_t)nq * 128;
        hipMemsetAsync(d_ws, 0, (size_t)nq * 129 * sizeof(float), stream);
        edge_atomic_kernel<<<(E + 255) / 256, 256, 0, stream>>>(
            rndata, qpos, lpos, dst, src, W0, b0, W1, b1, W2, b2, fagg, fcnt, E);
        proj_kernel<<<(nq + 255) / 256, 256, 0, stream>>>(
            fagg, fcnt, P0, pb0, P1, pb1, (float*)d_out, nq);
    }
}

// Round 3
// 3764.581 us; speedup vs baseline: 1.8357x; 1.8271x over previous
//
#include <hip/hip_runtime.h>

// GNODecoder round 3: counting-sort by dst, then ONE fused kernel:
// block owns 64 consecutive queries + their contiguous sorted edge range.
// Lane-per-edge MLP (wave-uniform weights -> s_load), k*rsrc accumulated
// into per-query LDS accumulators (ds_add_f32, stride 129 kills bank
// conflicts across queries), then wave 0 does mean + projection MLP and
// writes out[q,4]. No rep[E,128] (512 MB) and no agg[NQ,128] (51 MB):
// workspace = sort arrays only (~9.2 MB), guaranteed to fit.

#define QB 64  // queries per block

__device__ __forceinline__ float gelu_f(float x) {
    // jax.nn.gelu default (approximate=True, tanh form)
    float x3 = x * x * x;
    float t  = 0.7978845608028654f * fmaf(0.044715f, x3, x);
    float e  = __expf(2.0f * t);
    float r  = __builtin_amdgcn_rcpf(e + 1.0f);
    return 0.5f * x * (1.0f + (1.0f - 2.0f * r));
}

// ---------- sort machinery ----------

__global__ void hist_kernel(const int* __restrict__ dst, int* __restrict__ hist, int E) {
    int e = blockIdx.x * blockDim.x + threadIdx.x;
    if (e < E) atomicAdd(&hist[dst[e]], 1);
}

// exclusive scan of hist[0..n-1] -> start[0..n], single 1024-thread workgroup
__global__ __launch_bounds__(1024) void scan_kernel(const int* __restrict__ hist,
                                                    int* __restrict__ start, int n) {
    __shared__ int wsum[16];
    __shared__ int woff[16];
    int tid = threadIdx.x;
    int lane = tid & 63, wid = tid >> 6;
    int carry = 0;  // meaningful on tid 0 only
    for (int base = 0; base < n; base += 1024) {
        int i = base + tid;
        int v = (i < n) ? hist[i] : 0;
        int incl = v;
#pragma unroll
        for (int off = 1; off < 64; off <<= 1) {
            int t = __shfl_up(incl, off, 64);
            if (lane >= off) incl += t;
        }
        if (lane == 63) wsum[wid] = incl;
        __syncthreads();
        if (tid == 0) {
            int acc = carry;
#pragma unroll
            for (int w = 0; w < 16; ++w) { woff[w] = acc; acc += wsum[w]; }
            carry = acc;
        }
        __syncthreads();
        if (i < n) start[i] = woff[wid] + incl - v;  // exclusive
        __syncthreads();
    }
    if (threadIdx.x == 0) start[n] = carry;
}

__global__ void scatter_kernel(const int* __restrict__ dst, const int* __restrict__ src,
                               const int* __restrict__ start, int* __restrict__ cursor,
                               int* __restrict__ dsts, int* __restrict__ srcs, int E) {
    int e = blockIdx.x * blockDim.x + threadIdx.x;
    if (e >= E) return;
    int d = dst[e];
    int pos = start[d] + atomicAdd(&cursor[d], 1);
    dsts[pos] = d;
    srcs[pos] = src[e];
}

// ---------- fused edge-MLP + segmented-mean + projection ----------

__global__ __launch_bounds__(256) void fused_kernel(
    const float* __restrict__ rndata,   // [NL,128]
    const float* __restrict__ qpos,     // [NQ,3]
    const float* __restrict__ lpos,     // [NL,3]
    const int*   __restrict__ dsts,     // [E] sorted by dst
    const int*   __restrict__ srcs,     // [E] matching
    const int*   __restrict__ start,    // [NQ+1]
    const float* __restrict__ W0, const float* __restrict__ b0,
    const float* __restrict__ W1, const float* __restrict__ b1,
    const float* __restrict__ W2, const float* __restrict__ b2,
    const float* __restrict__ P0, const float* __restrict__ pb0,
    const float* __restrict__ P1, const float* __restrict__ pb1,
    float* __restrict__ out,            // [NQ,4]
    int nq)
{
    // stride 129: 129 % 32 == 1 -> per channel, distinct queries hit
    // distinct LDS banks; epilogue reads sacc[l*129+i] are 2-way (free)
    __shared__ float sacc[QB * 129];

    int q0   = blockIdx.x * QB;
    int qend = min(q0 + QB, nq);

    for (int i = threadIdx.x; i < QB * 129; i += 256) sacc[i] = 0.f;
    __syncthreads();

    int e_begin = start[q0];
    int e_end   = start[qend];

    for (int base = e_begin; base < e_end; base += 256) {
        int  e     = base + threadIdx.x;
        bool valid = (e < e_end);
        int  d = valid ? dsts[e] : q0;
        int  s = valid ? srcs[e] : 0;
        int  ql = d - q0;

        float q0c = qpos[d * 3 + 0], q1c = qpos[d * 3 + 1], q2c = qpos[d * 3 + 2];
        float l0c = lpos[s * 3 + 0], l1c = lpos[s * 3 + 1], l2c = lpos[s * 3 + 2];

        // layer 0: [6] -> [64], gelu
        float h0[64];
#pragma unroll
        for (int j = 0; j < 64; ++j) {
            float a = b0[j];
            a = fmaf(q0c, W0[0 * 64 + j], a);
            a = fmaf(q1c, W0[1 * 64 + j], a);
            a = fmaf(q2c, W0[2 * 64 + j], a);
            a = fmaf(l0c, W0[3 * 64 + j], a);
            a = fmaf(l1c, W0[4 * 64 + j], a);
            a = fmaf(l2c, W0[5 * 64 + j], a);
            h0[j] = gelu_f(a);
        }

        // layer 1: [64] -> [64], gelu
        float h1[64];
#pragma unroll
        for (int jj = 0; jj < 64; jj += 8) {
            float acc[8];
#pragma unroll
            for (int u = 0; u < 8; ++u) acc[u] = b1[jj + u];
#pragma unroll
            for (int i2 = 0; i2 < 64; ++i2) {
                float h = h0[i2];
#pragma unroll
                for (int u = 0; u < 8; ++u)
                    acc[u] = fmaf(h, W1[i2 * 64 + jj + u], acc[u]);
            }
#pragma unroll
            for (int u = 0; u < 8; ++u) h1[jj + u] = gelu_f(acc[u]);
        }

        // layer 2: [64] -> [128], * rndata[src], accumulate into LDS per-query
        const float4* r4   = (const float4*)(rndata + (size_t)s * 128);
        float*        aacc = &sacc[ql * 129];
#pragma unroll 1
        for (int jj = 0; jj < 128; jj += 8) {
            float acc[8];
#pragma unroll
            for (int u = 0; u < 8; ++u) acc[u] = b2[jj + u];
#pragma unroll
            for (int i2 = 0; i2 < 64; ++i2) {
                float h = h1[i2];
#pragma unroll
                for (int u = 0; u < 8; ++u)
                    acc[u] = fmaf(h, W2[i2 * 128 + jj + u], acc[u]);
            }
            float4 ra = r4[jj / 4], rb = r4[jj / 4 + 1];
            if (valid) {
                atomicAdd(&aacc[jj + 0], acc[0] * ra.x);
                atomicAdd(&aacc[jj + 1], acc[1] * ra.y);
                atomicAdd(&aacc[jj + 2], acc[2] * ra.z);
                atomicAdd(&aacc[jj + 3], acc[3] * ra.w);
                atomicAdd(&aacc[jj + 4], acc[4] * rb.x);
                atomicAdd(&aacc[jj + 5], acc[5] * rb.y);
                atomicAdd(&aacc[jj + 6], acc[6] * rb.z);
                atomicAdd(&aacc[jj + 7], acc[7] * rb.w);
            }
        }
    }
    __syncthreads();

    // epilogue: wave 0, lane-per-query mean + projection MLP
    if (threadIdx.x < 64) {
        int q = q0 + threadIdx.x;
        if (q < nq) {
            int   deg = start[q + 1] - start[q];
            float inv = 1.0f / fmaxf((float)deg, 1.0f);
            const float* aq = &sacc[threadIdx.x * 129];

            float o0 = pb1[0], o1 = pb1[1], o2 = pb1[2], o3 = pb1[3];
#pragma unroll 1
            for (int jj = 0; jj < 256; jj += 8) {
                float acc[8];
#pragma unroll
                for (int u = 0; u < 8; ++u) acc[u] = pb0[jj + u];
#pragma unroll
                for (int i = 0; i < 128; ++i) {
                    float av = aq[i] * inv;
#pragma unroll
                    for (int u = 0; u < 8; ++u)
                        acc[u] = fmaf(av, P0[i * 256 + jj + u], acc[u]);
                }
#pragma unroll
                for (int u = 0; u < 8; ++u) {
                    float h = gelu_f(acc[u]);
                    o0 = fmaf(h, P1[(jj + u) * 4 + 0], o0);
                    o1 = fmaf(h, P1[(jj + u) * 4 + 1], o1);
                    o2 = fmaf(h, P1[(jj + u) * 4 + 2], o2);
                    o3 = fmaf(h, P1[(jj + u) * 4 + 3], o3);
                }
            }
            float4* o4 = (float4*)(out + (size_t)q * 4);
            *o4 = make_float4(o0, o1, o2, o3);
        }
    }
}

extern "C" void kernel_launch(void* const* d_in, const int* in_sizes, int n_in,
                              void* d_out, int out_size, void* d_ws, size_t ws_size,
                              hipStream_t stream)
{
    const float* rndata = (const float*)d_in[0];
    const float* qpos   = (const float*)d_in[1];
    const float* lpos   = (const float*)d_in[2];
    const int*   dst    = (const int*)d_in[3];
    const int*   src    = (const int*)d_in[4];
    const float* W0  = (const float*)d_in[5];
    const float* b0  = (const float*)d_in[6];
    const float* W1  = (const float*)d_in[7];
    const float* b1  = (const float*)d_in[8];
    const float* W2  = (const float*)d_in[9];
    const float* b2  = (const float*)d_in[10];
    const float* P0  = (const float*)d_in[11];
    const float* pb0 = (const float*)d_in[12];
    const float* P1  = (const float*)d_in[13];
    const float* pb1 = (const float*)d_in[14];

    int nq = in_sizes[1] / 3;
    int E  = in_sizes[3];

    // workspace: hist, cursor, start, dsts, srcs  (~9.2 MB total)
    size_t off = 0;
    auto alloc = [&](size_t bytes) {
        void* p = (char*)d_ws + off;
        off += (bytes + 15) & ~(size_t)15;
        return p;
    };
    int* hist   = (int*)alloc((size_t)nq * sizeof(int));
    int* cursor = (int*)alloc((size_t)nq * sizeof(int));
    int* start  = (int*)alloc((size_t)(nq + 1) * sizeof(int));
    int* dsts   = (int*)alloc((size_t)E * sizeof(int));
    int* srcs   = (int*)alloc((size_t)E * sizeof(int));
    (void)ws_size;

    // zero hist + cursor (adjacent, both 16B-padded)
    size_t histpad = ((size_t)nq * sizeof(int) + 15) & ~(size_t)15;
    hipMemsetAsync(hist, 0, 2 * histpad, stream);

    hist_kernel<<<(E + 255) / 256, 256, 0, stream>>>(dst, hist, E);
    scan_kernel<<<1, 1024, 0, stream>>>(hist, start, nq);
    scatter_kernel<<<(E + 255) / 256, 256, 0, stream>>>(dst, src, start, cursor, dsts, srcs, E);
    fused_kernel<<<(nq + QB - 1) / QB, 256, 0, stream>>>(
        rndata, qpos, lpos, dsts, srcs, start,
        W0, b0, W1, b1, W2, b2, P0, pb0, P1, pb1,
        (float*)d_out, nq);
}

// Round 4
// 3051.980 us; speedup vs baseline: 2.2644x; 1.2335x over previous
//
#include <hip/hip_runtime.h>

// GNODecoder round 4: weight delivery was the wall (s_load of 48 KB weights
// thrashing the scalar cache -> 23% VALUBusy). Stage all edge-MLP weights in
// LDS (wave-uniform ds_read broadcast, constant offsets, parallel to VALU
// pipe). QB=24 keeps total LDS at 64,096 B -> 2 blocks/CU, 8 waves/CU.
// Epilogue writes mean to global agg; separate full-occupancy proj kernel.

#define QB 24  // queries per block (sacc 24*129*4 B; total LDS 64,096 B < 64 KB limit)

// float offsets into dynamic smem
#define OFF_W0   0        // [6*64]
#define OFF_B0   384      // [64]
#define OFF_W1   448      // [64*64]
#define OFF_B1   4544     // [64]
#define OFF_W2   4608     // [64*128]
#define OFF_B2   12800    // [128]
#define OFF_SACC 12928    // [QB*129]
#define SMEM_FLOATS (12928 + QB * 129)

__device__ __forceinline__ float gelu_f(float x) {
    // jax.nn.gelu default (approximate=True, tanh form)
    float x3 = x * x * x;
    float t  = 0.7978845608028654f * fmaf(0.044715f, x3, x);
    float e  = __expf(2.0f * t);
    float r  = __builtin_amdgcn_rcpf(e + 1.0f);
    return 0.5f * x * (1.0f + (1.0f - 2.0f * r));
}

// ---------- sort machinery (unchanged, proven) ----------

__global__ void hist_kernel(const int* __restrict__ dst, int* __restrict__ hist, int E) {
    int e = blockIdx.x * blockDim.x + threadIdx.x;
    if (e < E) atomicAdd(&hist[dst[e]], 1);
}

__global__ __launch_bounds__(1024) void scan_kernel(const int* __restrict__ hist,
                                                    int* __restrict__ start, int n) {
    __shared__ int wsum[16];
    __shared__ int woff[16];
    int tid = threadIdx.x;
    int lane = tid & 63, wid = tid >> 6;
    int carry = 0;  // meaningful on tid 0 only
    for (int base = 0; base < n; base += 1024) {
        int i = base + tid;
        int v = (i < n) ? hist[i] : 0;
        int incl = v;
#pragma unroll
        for (int off = 1; off < 64; off <<= 1) {
            int t = __shfl_up(incl, off, 64);
            if (lane >= off) incl += t;
        }
        if (lane == 63) wsum[wid] = incl;
        __syncthreads();
        if (tid == 0) {
            int acc = carry;
#pragma unroll
            for (int w = 0; w < 16; ++w) { woff[w] = acc; acc += wsum[w]; }
            carry = acc;
        }
        __syncthreads();
        if (i < n) start[i] = woff[wid] + incl - v;
        __syncthreads();
    }
    if (threadIdx.x == 0) start[n] = carry;
}

__global__ void scatter_kernel(const int* __restrict__ dst, const int* __restrict__ src,
                               const int* __restrict__ start, int* __restrict__ cursor,
                               int* __restrict__ dsts, int* __restrict__ srcs, int E) {
    int e = blockIdx.x * blockDim.x + threadIdx.x;
    if (e >= E) return;
    int d = dst[e];
    int pos = start[d] + atomicAdd(&cursor[d], 1);
    dsts[pos] = d;
    srcs[pos] = src[e];
}

// ---------- fused edge-MLP + segmented-mean (+ optional proj) ----------

template <bool FUSED_PROJ>
__global__ __launch_bounds__(256, 2) void fused_kernel(
    const float* __restrict__ rndata,   // [NL,128]
    const float* __restrict__ qpos,     // [NQ,3]
    const float* __restrict__ lpos,     // [NL,3]
    const int*   __restrict__ dsts,     // [E] sorted by dst
    const int*   __restrict__ srcs,     // [E]
    const int*   __restrict__ start,    // [NQ+1]
    const float* __restrict__ W0, const float* __restrict__ b0,
    const float* __restrict__ W1, const float* __restrict__ b1,
    const float* __restrict__ W2, const float* __restrict__ b2,
    const float* __restrict__ P0, const float* __restrict__ pb0,
    const float* __restrict__ P1, const float* __restrict__ pb1,
    float* __restrict__ agg,            // [NQ,128] mean (used if !FUSED_PROJ)
    float* __restrict__ out,            // [NQ,4]   (used if FUSED_PROJ)
    int nq)
{
    extern __shared__ float smem[];

    // ---- stage weights into LDS (all counts divisible by 4) ----
    {
        auto cp = [&](const float* g, int base_f, int nf) {
            const float4* g4 = (const float4*)g;
            float4* d4 = (float4*)(smem + base_f);
            for (int i = threadIdx.x; i < (nf >> 2); i += 256) d4[i] = g4[i];
        };
        cp(W0, OFF_W0, 384);
        cp(b0, OFF_B0, 64);
        cp(W1, OFF_W1, 4096);
        cp(b1, OFF_B1, 64);
        cp(W2, OFF_W2, 8192);
        cp(b2, OFF_B2, 128);
        for (int i = threadIdx.x; i < QB * 129; i += 256) smem[OFF_SACC + i] = 0.f;
    }
    __syncthreads();

    const float* sw0 = smem + OFF_W0;
    const float* sb0 = smem + OFF_B0;
    const float* sw1 = smem + OFF_W1;
    const float* sb1 = smem + OFF_B1;
    const float* sw2 = smem + OFF_W2;
    const float* sb2 = smem + OFF_B2;
    float*       sacc = smem + OFF_SACC;   // stride 129: conflict-free per query

    int q0   = blockIdx.x * QB;
    int qend = min(q0 + QB, nq);
    int e_begin = start[q0];
    int e_end   = start[qend];

    for (int base = e_begin; base < e_end; base += 256) {
        int  e     = base + threadIdx.x;
        bool valid = (e < e_end);
        int  d = valid ? dsts[e] : q0;
        int  s = valid ? srcs[e] : 0;
        int  ql = d - q0;

        float q0c = qpos[d * 3 + 0], q1c = qpos[d * 3 + 1], q2c = qpos[d * 3 + 2];
        float l0c = lpos[s * 3 + 0], l1c = lpos[s * 3 + 1], l2c = lpos[s * 3 + 2];

        // layer 0: [6] -> [64], gelu
        float h0[64];
#pragma unroll
        for (int j = 0; j < 64; ++j) {
            float a = sb0[j];
            a = fmaf(q0c, sw0[0 * 64 + j], a);
            a = fmaf(q1c, sw0[1 * 64 + j], a);
            a = fmaf(q2c, sw0[2 * 64 + j], a);
            a = fmaf(l0c, sw0[3 * 64 + j], a);
            a = fmaf(l1c, sw0[4 * 64 + j], a);
            a = fmaf(l2c, sw0[5 * 64 + j], a);
            h0[j] = gelu_f(a);
        }

        // layer 1: [64] -> [64], gelu
        float h1[64];
#pragma unroll
        for (int jj = 0; jj < 64; jj += 8) {
            float acc[8];
#pragma unroll
            for (int u = 0; u < 8; ++u) acc[u] = sb1[jj + u];
#pragma unroll
            for (int i2 = 0; i2 < 64; ++i2) {
                float h = h0[i2];
#pragma unroll
                for (int u = 0; u < 8; ++u)
                    acc[u] = fmaf(h, sw1[i2 * 64 + jj + u], acc[u]);
            }
#pragma unroll
            for (int u = 0; u < 8; ++u) h1[jj + u] = gelu_f(acc[u]);
        }

        // layer 2: [64] -> [128], * rndata[src], LDS per-query accumulate
        const float4* r4   = (const float4*)(rndata + (size_t)s * 128);
        float*        aacc = &sacc[ql * 129];
#pragma unroll 1
        for (int jj = 0; jj < 128; jj += 8) {
            float acc[8];
#pragma unroll
            for (int u = 0; u < 8; ++u) acc[u] = sb2[jj + u];
#pragma unroll
            for (int i2 = 0; i2 < 64; ++i2) {
                float h = h1[i2];
#pragma unroll
                for (int u = 0; u < 8; ++u)
                    acc[u] = fmaf(h, sw2[i2 * 128 + jj + u], acc[u]);
            }
            float4 ra = r4[jj / 4], rb = r4[jj / 4 + 1];
            if (valid) {
                atomicAdd(&aacc[jj + 0], acc[0] * ra.x);
                atomicAdd(&aacc[jj + 1], acc[1] * ra.y);
                atomicAdd(&aacc[jj + 2], acc[2] * ra.z);
                atomicAdd(&aacc[jj + 3], acc[3] * ra.w);
                atomicAdd(&aacc[jj + 4], acc[4] * rb.x);
                atomicAdd(&aacc[jj + 5], acc[5] * rb.y);
                atomicAdd(&aacc[jj + 6], acc[6] * rb.z);
                atomicAdd(&aacc[jj + 7], acc[7] * rb.w);
            }
        }
    }
    __syncthreads();

    if (!FUSED_PROJ) {
        // write per-query mean to global agg (coalesced)
        for (int idx = threadIdx.x; idx < QB * 128; idx += 256) {
            int ql = idx >> 7, c = idx & 127;
            int q  = q0 + ql;
            if (q < nq) {
                int   deg = start[q + 1] - start[q];
                float inv = 1.0f / fmaxf((float)deg, 1.0f);
                agg[(size_t)q * 128 + c] = sacc[ql * 129 + c] * inv;
            }
        }
    } else {
        // fallback: full projection per query, lanes 0..QB-1
        if (threadIdx.x < QB) {
            int q = q0 + threadIdx.x;
            if (q < nq) {
                int   deg = start[q + 1] - start[q];
                float inv = 1.0f / fmaxf((float)deg, 1.0f);
                const float* aq = &sacc[threadIdx.x * 129];
                float o0 = pb1[0], o1 = pb1[1], o2 = pb1[2], o3 = pb1[3];
#pragma unroll 1
                for (int jj = 0; jj < 256; jj += 8) {
                    float acc[8];
#pragma unroll
                    for (int u = 0; u < 8; ++u) acc[u] = pb0[jj + u];
#pragma unroll
                    for (int i = 0; i < 128; ++i) {
                        float av = aq[i] * inv;
#pragma unroll
                        for (int u = 0; u < 8; ++u)
                            acc[u] = fmaf(av, P0[i * 256 + jj + u], acc[u]);
                    }
#pragma unroll
                    for (int u = 0; u < 8; ++u) {
                        float h = gelu_f(acc[u]);
                        o0 = fmaf(h, P1[(jj + u) * 4 + 0], o0);
                        o1 = fmaf(h, P1[(jj + u) * 4 + 1], o1);
                        o2 = fmaf(h, P1[(jj + u) * 4 + 2], o2);
                        o3 = fmaf(h, P1[(jj + u) * 4 + 3], o3);
                    }
                }
                float4* o4 = (float4*)(out + (size_t)q * 4);
                *o4 = make_float4(o0, o1, o2, o3);
            }
        }
    }
}

// ---------- projection (full occupancy, agg already holds the mean) ----------

__global__ __launch_bounds__(256) void proj_kernel(
    const float* __restrict__ agg,      // [NQ,128] mean
    const float* __restrict__ P0, const float* __restrict__ pb0,
    const float* __restrict__ P1, const float* __restrict__ pb1,
    float* __restrict__ out, int nq)
{
    int q = blockIdx.x * blockDim.x + threadIdx.x;
    if (q >= nq) return;

    float a[128];
    const float4* ag4 = (const float4*)(agg + (size_t)q * 128);
#pragma unroll
    for (int i = 0; i < 32; ++i) {
        float4 v = ag4[i];
        a[4 * i + 0] = v.x;
        a[4 * i + 1] = v.y;
        a[4 * i + 2] = v.z;
        a[4 * i + 3] = v.w;
    }

    float o0 = pb1[0], o1 = pb1[1], o2 = pb1[2], o3 = pb1[3];
#pragma unroll 1
    for (int jj = 0; jj < 256; jj += 8) {
        float acc[8];
#pragma unroll
        for (int u = 0; u < 8; ++u) acc[u] = pb0[jj + u];
#pragma unroll
        for (int i = 0; i < 128; ++i) {
            float av = a[i];
#pragma unroll
            for (int u = 0; u < 8; ++u)
                acc[u] = fmaf(av, P0[i * 256 + jj + u], acc[u]);
        }
#pragma unroll
        for (int u = 0; u < 8; ++u) {
            float h = gelu_f(acc[u]);
            o0 = fmaf(h, P1[(jj + u) * 4 + 0], o0);
            o1 = fmaf(h, P1[(jj + u) * 4 + 1], o1);
            o2 = fmaf(h, P1[(jj + u) * 4 + 2], o2);
            o3 = fmaf(h, P1[(jj + u) * 4 + 3], o3);
        }
    }
    float4* o4 = (float4*)(out + (size_t)q * 4);
    *o4 = make_float4(o0, o1, o2, o3);
}

extern "C" void kernel_launch(void* const* d_in, const int* in_sizes, int n_in,
                              void* d_out, int out_size, void* d_ws, size_t ws_size,
                              hipStream_t stream)
{
    const float* rndata = (const float*)d_in[0];
    const float* qpos   = (const float*)d_in[1];
    const float* lpos   = (const float*)d_in[2];
    const int*   dst    = (const int*)d_in[3];
    const int*   src    = (const int*)d_in[4];
    const float* W0  = (const float*)d_in[5];
    const float* b0  = (const float*)d_in[6];
    const float* W1  = (const float*)d_in[7];
    const float* b1  = (const float*)d_in[8];
    const float* W2  = (const float*)d_in[9];
    const float* b2  = (const float*)d_in[10];
    const float* P0  = (const float*)d_in[11];
    const float* pb0 = (const float*)d_in[12];
    const float* P1  = (const float*)d_in[13];
    const float* pb1 = (const float*)d_in[14];

    int nq = in_sizes[1] / 3;
    int E  = in_sizes[3];

    // ws layout: [agg nq*128 (path A only)] [hist] [cursor] [start] [dsts] [srcs]
    size_t agg_bytes  = (size_t)nq * 128 * sizeof(float);
    size_t sort_bytes = 0;
    {
        size_t o = 0;
        o += ((size_t)nq * sizeof(int) + 15) & ~(size_t)15;       // hist
        o += ((size_t)nq * sizeof(int) + 15) & ~(size_t)15;       // cursor
        o += ((size_t)(nq + 1) * sizeof(int) + 15) & ~(size_t)15; // start
        o += ((size_t)E * sizeof(int) + 15) & ~(size_t)15;        // dsts
        o += ((size_t)E * sizeof(int) + 15) & ~(size_t)15;        // srcs
        sort_bytes = o;
    }
    bool path_a = (agg_bytes + sort_bytes) <= ws_size;

    size_t off = path_a ? agg_bytes : 0;
    auto alloc = [&](size_t bytes) {
        void* p = (char*)d_ws + off;
        off += (bytes + 15) & ~(size_t)15;
        return p;
    };
    float* agg   = (float*)d_ws;  // valid in path A only
    int* hist    = (int*)alloc((size_t)nq * sizeof(int));
    int* cursor  = (int*)alloc((size_t)nq * sizeof(int));
    int* start   = (int*)alloc((size_t)(nq + 1) * sizeof(int));
    int* dsts    = (int*)alloc((size_t)E * sizeof(int));
    int* srcs    = (int*)alloc((size_t)E * sizeof(int));

    size_t histpad = ((size_t)nq * sizeof(int) + 15) & ~(size_t)15;
    hipMemsetAsync(hist, 0, 2 * histpad, stream);

    hist_kernel<<<(E + 255) / 256, 256, 0, stream>>>(dst, hist, E);
    scan_kernel<<<1, 1024, 0, stream>>>(hist, start, nq);
    scatter_kernel<<<(E + 255) / 256, 256, 0, stream>>>(dst, src, start, cursor, dsts, srcs, E);

    int nblocks = (nq + QB - 1) / QB;
    size_t smem_bytes = (size_t)SMEM_FLOATS * sizeof(float);  // 64,096 B

    if (path_a) {
        fused_kernel<false><<<nblocks, 256, smem_bytes, stream>>>(
            rndata, qpos, lpos, dsts, srcs, start,
            W0, b0, W1, b1, W2, b2, P0, pb0, P1, pb1,
            agg, nullptr, nq);
        proj_kernel<<<(nq + 255) / 256, 256, 0, stream>>>(
            agg, P0, pb0, P1, pb1, (float*)d_out, nq);
    } else {
        fused_kernel<true><<<nblocks, 256, smem_bytes, stream>>>(
            rndata, qpos, lpos, dsts, srcs, start,
            W0, b0, W1, b1, W2, b2, P0, pb0, P1, pb1,
            nullptr, (float*)d_out, nq);
    }
}